// Round 1
// baseline (17.476 us; speedup 1.0000x reference)
//
#include <hip/hip_runtime.h>

// L_x1 L_x2 of RBF kernel k(x1,x2)=exp(-||x1-x2||^2/(2 l^2)) in D=2.
// Closed form: with a = 1/l^2, t = a*r^2,
//   L_x1 L_x2 k = exp(-t/2) * a^2 * (t^2 - 2(D+2) t + D(D+2))
//               = exp(-t/2) * a^2 * (t^2 - 8 t + 8)   for D=2.

#define N1 4096
#define N2 4096

__global__ __launch_bounds__(256) void poisson_lxlx_kernel(
    const float* __restrict__ X1, const float* __restrict__ X2,
    const float* __restrict__ ls, float* __restrict__ out)
{
    const int i  = blockIdx.y;                               // row (X1 point)
    const int j4 = blockIdx.x * blockDim.x + threadIdx.x;    // group of 4 cols
    const int j  = j4 * 4;
    if (j >= N2) return;

    const float l = ls[0];
    const float a = 1.0f / (l * l);
    const float a2 = a * a;

    const float x10 = X1[2 * i];
    const float x11 = X1[2 * i + 1];

    // 4 consecutive X2 points = 8 contiguous floats
    const float4 p0 = *reinterpret_cast<const float4*>(X2 + 2 * (size_t)j);
    const float4 p1 = *reinterpret_cast<const float4*>(X2 + 2 * (size_t)j + 4);

    float4 r;
    {
        float d0 = x10 - p0.x, d1 = x11 - p0.y;
        float t = a * (d0 * d0 + d1 * d1);
        r.x = __expf(-0.5f * t) * a2 * (t * t - 8.0f * t + 8.0f);
    }
    {
        float d0 = x10 - p0.z, d1 = x11 - p0.w;
        float t = a * (d0 * d0 + d1 * d1);
        r.y = __expf(-0.5f * t) * a2 * (t * t - 8.0f * t + 8.0f);
    }
    {
        float d0 = x10 - p1.x, d1 = x11 - p1.y;
        float t = a * (d0 * d0 + d1 * d1);
        r.z = __expf(-0.5f * t) * a2 * (t * t - 8.0f * t + 8.0f);
    }
    {
        float d0 = x10 - p1.z, d1 = x11 - p1.w;
        float t = a * (d0 * d0 + d1 * d1);
        r.w = __expf(-0.5f * t) * a2 * (t * t - 8.0f * t + 8.0f);
    }

    *reinterpret_cast<float4*>(out + (size_t)i * N2 + j) = r;
}

extern "C" void kernel_launch(void* const* d_in, const int* in_sizes, int n_in,
                              void* d_out, int out_size, void* d_ws, size_t ws_size,
                              hipStream_t stream) {
    const float* X1 = (const float*)d_in[0];
    const float* X2 = (const float*)d_in[1];
    const float* ls = (const float*)d_in[2];
    float* out = (float*)d_out;

    dim3 block(256);
    dim3 grid((N2 / 4 + 255) / 256, N1);  // (4, 4096)
    poisson_lxlx_kernel<<<grid, block, 0, stream>>>(X1, X2, ls, out);
}